// Round 14
// baseline (392.261 us; speedup 1.0000x reference)
//
#include <hip/hip_runtime.h>

// Content_SA: instance-norm -> f/g/h 1x1 convs -> attention(QK^T softmax, PV) -> o conv + residual.
// B=4, C=512, H=W=64 (N=4096).
// Algebra: energy[n,m] = xn(n)^T M xn(m) + u[m] (+ query-const, cancels), M = f_w^T g_w (fp32).
//          out = W.(x.att^T) + bias2 + x, W = o_w.h_w (fp32), bias2 = o_w.h_b + o_b.
// Precision: M,W,Z,xn,x_v all f16 (single rounding from fp32-grade values); softmax fp32.
// R14: flash = R11 skeleton + QK 4-chain parity split ONLY (+16 transient VGPR; R12's spill
// came from the 128-key state, not the split). Weight-prep kernels merged into one launch.

typedef __bf16 bf16_t;
typedef _Float16 f16_t;
typedef _Float16 f16x8 __attribute__((ext_vector_type(8)));
typedef float f32x4 __attribute__((ext_vector_type(4)));

#define LOG2E 1.44269504088896340736f

__device__ __forceinline__ void gload16(const void* g, void* l) {
  __builtin_amdgcn_global_load_lds(
      (const __attribute__((address_space(1))) void*)g,
      (__attribute__((address_space(3))) void*)l, 16, 0, 0);
}

// ---------------- instance-norm statistics + x -> f16 cast (xv[b][c][n]) ----------------
__global__ void __launch_bounds__(256) stats_k(const float* __restrict__ x,
                                               float* __restrict__ mu,
                                               float* __restrict__ rs,
                                               f16_t* __restrict__ xv) {
  const int bc = blockIdx.x;
  const float4* row = (const float4*)(x + (size_t)bc * 4096);
  f16_t* vrow = xv + (size_t)bc * 4096;
  float s = 0.f, ss = 0.f;
  for (int i = threadIdx.x; i < 1024; i += 256) {
    float4 v = row[i];
    s += v.x + v.y + v.z + v.w;
    ss += v.x * v.x + v.y * v.y + v.z * v.z + v.w * v.w;
    alignas(8) f16_t h[4];
    h[0] = (f16_t)v.x; h[1] = (f16_t)v.y; h[2] = (f16_t)v.z; h[3] = (f16_t)v.w;
    *(uint2*)(vrow + i * 4) = *(const uint2*)h;
  }
#pragma unroll
  for (int o = 32; o >= 1; o >>= 1) {
    s += __shfl_down(s, o);
    ss += __shfl_down(ss, o);
  }
  __shared__ float as_[4], ass_[4];
  const int w = threadIdx.x >> 6;
  if ((threadIdx.x & 63) == 0) { as_[w] = s; ass_[w] = ss; }
  __syncthreads();
  if (threadIdx.x == 0) {
    float st = as_[0] + as_[1] + as_[2] + as_[3];
    float sst = ass_[0] + ass_[1] + ass_[2] + ass_[3];
    float m = st * (1.f / 4096.f);
    float var = sst * (1.f / 4096.f) - m * m;
    mu[bc] = m;
    rs[bc] = rsqrtf(var + 1e-5f);
  }
}

// ---------------- merged weight-prep: M, W, v, bias2 in ONE launch (132 blocks) ----------------
__device__ void mt_body(const float* __restrict__ A, const float* __restrict__ B,
                        f16_t* __restrict__ Out, int it, int jt, float* sm, bool bIsJK) {
  // Out[j][i] = sum_c A[c][i] * (bIsJK ? B[j][c] : B[c][j]); 64x64 tile at (it, jt).
  float* Fs = sm;          // [32][64]
  float* Gs = sm + 2048;   // bIsJK ? [64][33] : [32][64]
  const int t = threadIdx.x;
  float acc[16];
#pragma unroll
  for (int i = 0; i < 16; ++i) acc[i] = 0.f;
  const int jl = t >> 2, ib = (t & 3) * 16;
  const int lr = t >> 4, lc4 = (t & 15) * 4;
  for (int cc = 0; cc < 16; ++cc) {
    __syncthreads();
#pragma unroll
    for (int rep = 0; rep < 2; ++rep) {
      const int r = lr + rep * 16;
      *(float4*)&Fs[r * 64 + lc4] = *(const float4*)(A + (size_t)(cc * 32 + r) * 512 + it * 64 + lc4);
      if (!bIsJK)
        *(float4*)&Gs[r * 64 + lc4] = *(const float4*)(B + (size_t)(cc * 32 + r) * 512 + jt * 64 + lc4);
    }
    if (bIsJK) {
      const int oj = t >> 2, ok = (t & 3) * 8;
      const float4 a = *(const float4*)(B + (size_t)(jt * 64 + oj) * 512 + cc * 32 + ok);
      const float4 bq = *(const float4*)(B + (size_t)(jt * 64 + oj) * 512 + cc * 32 + ok + 4);
      Gs[oj * 33 + ok] = a.x; Gs[oj * 33 + ok + 1] = a.y;
      Gs[oj * 33 + ok + 2] = a.z; Gs[oj * 33 + ok + 3] = a.w;
      Gs[oj * 33 + ok + 4] = bq.x; Gs[oj * 33 + ok + 5] = bq.y;
      Gs[oj * 33 + ok + 6] = bq.z; Gs[oj * 33 + ok + 7] = bq.w;
    }
    __syncthreads();
#pragma unroll
    for (int c = 0; c < 32; ++c) {
      const float gv = bIsJK ? Gs[jl * 33 + c] : Gs[c * 64 + jl];
#pragma unroll
      for (int ii = 0; ii < 16; ++ii) acc[ii] += gv * Fs[c * 64 + ib + ii];
    }
  }
  alignas(16) f16_t hi[16];
#pragma unroll
  for (int ii = 0; ii < 16; ++ii) hi[ii] = (f16_t)acc[ii];
  const size_t o = (size_t)(jt * 64 + jl) * 512 + it * 64 + ib;
  *(uint4*)(Out + o) = *(const uint4*)hi;
  *(uint4*)(Out + o + 8) = *(const uint4*)(hi + 8);
}

__global__ void __launch_bounds__(256) prep_k(const float* __restrict__ fw,
                                              const float* __restrict__ gw,
                                              const float* __restrict__ hw,
                                              const float* __restrict__ ow,
                                              const float* __restrict__ fb,
                                              const float* __restrict__ hb,
                                              const float* __restrict__ ob,
                                              f16_t* __restrict__ Mh,
                                              f16_t* __restrict__ Wf,
                                              float* __restrict__ vv,
                                              float* __restrict__ b2) {
  __shared__ float sm[2048 + 64 * 33];
  const int bb = blockIdx.x;
  if (bb < 64) {
    mt_body(fw, gw, Mh, bb & 7, bb >> 3, sm, false);        // M^T[j][i] = sum_c fw[c][i] gw[c][j]
  } else if (bb < 128) {
    mt_body(hw, ow, Wf, (bb - 64) & 7, (bb - 64) >> 3, sm, true);  // W[j][i] = sum_k ow[j][k] hw[k][i]
  } else if (bb < 130) {
    const int j = (bb - 128) * 256 + threadIdx.x;
    float s = 0.f;
    for (int c = 0; c < 512; ++c) s += gw[(size_t)c * 512 + j] * fb[c];
    vv[j] = s;
  } else {
    const int j = (bb - 130) * 256 + threadIdx.x;
    float s = 0.f;
    for (int c = 0; c < 512; ++c) s += ow[(size_t)j * 512 + c] * hb[c];
    b2[j] = s + ob[j];
  }
}

// ---------------- u[b][m] = v . xn(m) ----------------
__global__ void __launch_bounds__(256) u_k(const float* __restrict__ v,
                                           const f16_t* __restrict__ xf,
                                           float* __restrict__ u) {
  const int w = threadIdx.x >> 6, lane = threadIdx.x & 63;
  const int m = blockIdx.x * 4 + w;
  const int b = blockIdx.y;
  const size_t o = ((size_t)b * 4096 + m) * 512 + lane * 8;
  const f16x8 vh = *(const f16x8*)(xf + o);
  const float4 v0 = *(const float4*)(v + lane * 8);
  const float4 v1 = *(const float4*)(v + lane * 8 + 4);
  float s = 0.f;
  const float* vp = &v0.x;
#pragma unroll
  for (int e = 0; e < 4; ++e) s += (float)vh[e] * vp[e];
  const float* vq = &v1.x;
#pragma unroll
  for (int e = 0; e < 4; ++e) s += (float)vh[4 + e] * vq[e];
#pragma unroll
  for (int o2 = 32; o2 >= 1; o2 >>= 1) s += __shfl_down(s, o2);
  if (lane == 0) u[(size_t)b * 4096 + m] = s;
}

// ---------------- normalize + transpose: x[b][c][n] -> xf (norm f16) [b][n][c] ----------------
__global__ void __launch_bounds__(256) normt_k(const float* __restrict__ x,
                                               const float* __restrict__ mu,
                                               const float* __restrict__ rs,
                                               f16_t* __restrict__ xf) {
  __shared__ float tile[64][65];
  const int t = threadIdx.x;
  const int nt = blockIdx.x, ct = blockIdx.y, b = blockIdx.z;
  const float* src = x + ((size_t)b * 512 + ct * 64) * 4096 + nt * 64;
  {
    const int r = t >> 4, cq = (t & 15) * 4;
#pragma unroll
    for (int it = 0; it < 4; ++it) {
      const int rr = r + it * 16;
      const float4 v = *(const float4*)(src + (size_t)rr * 4096 + cq);
      tile[rr][cq] = v.x; tile[rr][cq + 1] = v.y;
      tile[rr][cq + 2] = v.z; tile[rr][cq + 3] = v.w;
    }
  }
  __syncthreads();
  const int n = t & 63, ch = t >> 6;
  alignas(16) f16_t vf[16];
#pragma unroll
  for (int i = 0; i < 16; ++i) {
    const int c = ch * 16 + i;
    const float v = tile[c][n];
    const int gc = b * 512 + ct * 64 + c;
    vf[i] = (f16_t)((v - mu[gc]) * rs[gc]);
  }
  const size_t o = ((size_t)b * 4096 + nt * 64 + n) * 512 + ct * 64 + ch * 16;
  *(uint4*)(xf + o) = *(const uint4*)vf;
  *(uint4*)(xf + o + 8) = *(const uint4*)(vf + 8);
}

// ---------------- f16 GEMM (double-buffered, stage-ahead): C[m][n] = A[m][k].Bt[n][k], K=512 ----------------
template <typename OT, int BIAS, bool RESID>
__global__ void __launch_bounds__(256) gemm_k(const f16_t* __restrict__ A,
                                              const f16_t* __restrict__ Bt,
                                              OT* __restrict__ C,
                                              const float* __restrict__ biasM,
                                              const float* __restrict__ biasN,
                                              const float* __restrict__ resid,
                                              long sAb, long sBb, long sCb, int ldC) {
  __shared__ alignas(16) f16_t As[2][128 * 64];
  __shared__ alignas(16) f16_t Bs[2][128 * 64];
  const int t = threadIdx.x;
  const int lane = t & 63;
  const int w = t >> 6;
  const int wr = w >> 1, wc = w & 1;
  const int l15 = lane & 15, lg = lane >> 4;
  const int b = blockIdx.z;
  const int m0 = blockIdx.y * 128, n0 = blockIdx.x * 128;
  const f16_t* Ab = A + (size_t)sAb * b + (size_t)m0 * 512;
  const f16_t* Bb = Bt + (size_t)sBb * b + (size_t)n0 * 512;
  const int srow = t >> 3;
  const int slot = t & 7;

  auto gstage = [&](int pb_, int ks_) {
#pragma unroll
    for (int r_ = 0; r_ < 4; ++r_) {
      const int rr_ = r_ * 32 + srow;
      const size_t go_ = (size_t)rr_ * 512 + ks_ * 64 + ((slot ^ (rr_ & 7)) * 8);
      gload16(Ab + go_, (char*)As[pb_] + r_ * 4096 + w * 1024);
      gload16(Bb + go_, (char*)Bs[pb_] + r_ * 4096 + w * 1024);
    }
  };

  const f32x4 z4 = {0.f, 0.f, 0.f, 0.f};
  f32x4 acc[4][4];
#pragma unroll
  for (int i = 0; i < 4; ++i)
#pragma unroll
    for (int j = 0; j < 4; ++j) acc[i][j] = z4;

  gstage(0, 0);
  __syncthreads();
  for (int ks = 0; ks < 8; ++ks) {
    const int pb = ks & 1;
    if (ks < 7) gstage(pb ^ 1, ks + 1);
#pragma unroll
    for (int kk = 0; kk < 2; ++kk) {
      f16x8 af[4], bfr[4];
#pragma unroll
      for (int i = 0; i < 4; ++i) {
        const int ra = wr * 64 + i * 16 + l15;
        af[i] = *(const f16x8*)((const char*)As[pb] + ra * 128 + (((kk * 4 + lg) ^ (ra & 7)) * 16));
        const int rb = wc * 64 + i * 16 + l15;
        bfr[i] = *(const f16x8*)((const char*)Bs[pb] + rb * 128 + (((kk * 4 + lg) ^ (rb & 7)) * 16));
      }
#pragma unroll
      for (int i = 0; i < 4; ++i)
#pragma unroll
        for (int j = 0; j < 4; ++j)
          acc[i][j] = __builtin_amdgcn_mfma_f32_16x16x32_f16(af[i], bfr[j], acc[i][j], 0, 0, 0);
    }
    __syncthreads();
  }
  OT* Cb = C + (size_t)sCb * b;
#pragma unroll
  for (int i = 0; i < 4; ++i) {
#pragma unroll
    for (int j = 0; j < 4; ++j) {
      const int n = n0 + wc * 64 + j * 16 + l15;
      float bn = 0.f;
      if (BIAS == 2) bn = biasN[n];
#pragma unroll
      for (int r = 0; r < 4; ++r) {
        const int m = m0 + wr * 64 + i * 16 + lg * 4 + r;
        float v = acc[i][j][r] + bn;
        if (BIAS == 1) v += biasM[m];
        if (RESID) v += resid[(size_t)sCb * b + (size_t)m * ldC + n];
        Cb[(size_t)m * ldC + n] = (OT)v;
      }
    }
  }
}

// ---------------- flash attention (R11 skeleton + QK parity-split): V = xv (raw x, f16) ----------------
// Q=Z[b][q][c] f16 in regs; K=xf[b][k][c] f16, LDS ch-half ping-pong (2x32KB); V=xv[b][c][k]
// reg-prefetch; out Oat_t[b][q][c]. 8 waves: wq=w&3 (16 q), wk=w>>2 (32 keys). 64 tiles.
__global__ void __launch_bounds__(512, 1) flash_k(const f16_t* __restrict__ Z,
                                                  const f16_t* __restrict__ X,
                                                  const float* __restrict__ u,
                                                  const f16_t* __restrict__ Hv,
                                                  f16_t* __restrict__ Oat_t) {
  __shared__ alignas(16) f16_t K[2][64 * 256];  // 2 x 32KB, 512B rows, slot-swizzled
  __shared__ alignas(16) f16_t P[64 * 72];      // 9KB, 144B rows (2-way bank alias = free)
  __shared__ float redm[4][2][16];
  __shared__ float reds[4][2][16];
  __shared__ float alds[64];
  __shared__ float llds[64];

  const int t = threadIdx.x;
  const int lane = t & 63;
  const int w = t >> 6;
  const int wq = w & 3, wk = w >> 2;
  const int l15 = lane & 15, lg = lane >> 4;
  const int bid = blockIdx.x;
  const int xcd = bid & 7;
  const int b = xcd >> 1;
  const int q0 = ((xcd & 1) * 32 + (bid >> 3)) * 64;

  const f16_t* Kb = X + (size_t)b * 4096 * 512;
  const f16_t* Vb = Hv + (size_t)b * 512 * 4096;
  const float* ub = u + (size_t)b * 4096;

  const int srow = w * 2 + (lane >> 5);
  const int slot32 = lane & 31;

  auto stagek = [&](int pb_, int kt_, int hf_) {
    const int k0_ = kt_ * 64;
#pragma unroll
    for (int r_ = 0; r_ < 4; ++r_) {
      const int row_ = r_ * 16 + srow;
      const size_t go_ = (size_t)(k0_ + row_) * 512 + hf_ * 256 + ((slot32 ^ (row_ & 7)) * 8);
      gload16(Kb + go_, (char*)K[pb_] + r_ * 8192 + w * 1024);
    }
  };

// QK on buffer PB, channel-half HF: 16 MFMA in 4 independent chains (parity split --
// compiler can't reassociate MFMA intrinsics; 2 chains left the pipe latency-bound),
// merged into sacc with 2 vector adds per chain-pair.
#define QKHALF(PB, HF)                                                                        \
  do {                                                                                        \
    f32x4 e0 = z4, e1 = z4, d0 = z4, d1 = z4;                                                 \
    _Pragma("unroll") for (int cwl_ = 0; cwl_ < 8; ++cwl_) {                                  \
      const f16x8 qf_ = qf[(HF) * 8 + cwl_];                                                  \
      const int key0_ = 32 * wk + l15;                                                        \
      const int key1_ = 32 * wk + 16 + l15;                                                   \
      const f16x8 kf0_ = *(const f16x8*)((const char*)K[PB] + key0_ * 512 +                   \
                                         (((cwl_ * 4 + lg) ^ (key0_ & 7)) * 16));             \
      const f16x8 kf1_ = *(const f16x8*)((const char*)K[PB] + key1_ * 512 +                   \
                                         (((cwl_ * 4 + lg) ^ (key1_ & 7)) * 16));             \
      if (cwl_ & 1) {                                                                         \
        d0 = __builtin_amdgcn_mfma_f32_16x16x32_f16(kf0_, qf_, d0, 0, 0, 0);                  \
        d1 = __builtin_amdgcn_mfma_f32_16x16x32_f16(kf1_, qf_, d1, 0, 0, 0);                  \
      } else {                                                                                \
        e0 = __builtin_amdgcn_mfma_f32_16x16x32_f16(kf0_, qf_, e0, 0, 0, 0);                  \
        e1 = __builtin_amdgcn_mfma_f32_16x16x32_f16(kf1_, qf_, e1, 0, 0, 0);                  \
      }                                                                                       \
    }                                                                                         \
    sacc[0] += e0 + d0;                                                                       \
    sacc[1] += e1 + d1;                                                                       \
  } while (0)

  // Q fragments in registers: q = q0 + 16*wq + l15, ch window cw*32 + lg*8
  f16x8 qf[16];
  {
    const size_t qo = ((size_t)b * 4096 + q0 + 16 * wq + l15) * 512 + lg * 8;
#pragma unroll
    for (int cw = 0; cw < 16; ++cw) qf[cw] = *(const f16x8*)(Z + qo + cw * 32);
  }
  stagek(0, 0, 0);

  const f32x4 z4 = {0.f, 0.f, 0.f, 0.f};
  f32x4 oacc[4][4];
#pragma unroll
  for (int i = 0; i < 4; ++i)
#pragma unroll
    for (int j = 0; j < 4; ++j) oacc[i][j] = z4;
  float m_run = -3.0e38f, l_run = 0.f;
  const int qrow = 16 * wq + l15;

  __syncthreads();  // buf0.half0 ready

  for (int kt = 0; kt < 64; ++kt) {
    const int k0 = kt * 64;
    f32x4 sacc[2] = {z4, z4};
    // u for this wave's 32 keys (register loads)
    const float4 u0 = *(const float4*)(ub + k0 + 32 * wk + 4 * lg);
    const float4 u1 = *(const float4*)(ub + k0 + 32 * wk + 16 + 4 * lg);
    stagek(1, kt, 1);  // half1 -> buf1, flies under QK0
    QKHALF(0, 0);
    __syncthreads();   // buf1 ready
    if (kt < 63) stagek(0, kt + 1, 0);  // next half0 -> buf0, flies under QK1+softmax
    // V prefetch for this tile
    f16x8 vpre[4][2];
#pragma unroll
    for (int ct = 0; ct < 4; ++ct) {
      const int c = 64 * w + 16 * ct + l15;
#pragma unroll
      for (int kk = 0; kk < 2; ++kk)
        vpre[ct][kk] = *(const f16x8*)(Vb + (size_t)c * 4096 + k0 + kk * 32 + lg * 8);
    }
    QKHALF(1, 1);
    // ---- u bias + per-lane max ----
    float pm = -3.0e38f;
    {
      const float* up0 = &u0.x;
      const float* up1 = &u1.x;
#pragma unroll
      for (int j = 0; j < 4; ++j) {
        sacc[0][j] += up0[j];
        sacc[1][j] += up1[j];
        pm = fmaxf(pm, fmaxf(sacc[0][j], sacc[1][j]));
      }
    }
    pm = fmaxf(pm, __shfl_xor(pm, 16));
    pm = fmaxf(pm, __shfl_xor(pm, 32));
    if (lane < 16) redm[wq][wk][lane] = pm;
    __syncthreads();
    // ---- softmax with defer-max (THR=8) ----
    const float m_tile = fmaxf(pm, redm[wq][wk ^ 1][l15]);
    float alpha;
    if (m_tile > m_run + 8.f) {
      alpha = exp2f((m_run - m_tile) * LOG2E);
      m_run = m_tile;
    } else {
      alpha = 1.f;
    }
    float ps = 0.f;
    {
      alignas(8) f16_t pk[4];
#pragma unroll
      for (int mf = 0; mf < 2; ++mf) {
#pragma unroll
        for (int j = 0; j < 4; ++j) {
          const float p = exp2f((sacc[mf][j] - m_run) * LOG2E);
          ps += p;
          pk[j] = (f16_t)p;
        }
        *(uint2*)((char*)P + qrow * 144 + 64 * wk + 32 * mf + 8 * lg) = *(const uint2*)pk;
      }
    }
    ps += __shfl_xor(ps, 16);
    ps += __shfl_xor(ps, 32);
    if (lane < 16) {
      reds[wq][wk][lane] = ps;
      if (wk == 0) alds[16 * wq + lane] = alpha;
    }
    __syncthreads();  // P / reds / alds ready
    const float s_tile = reds[wq][0][l15] + reds[wq][1][l15];
    l_run = l_run * alpha + s_tile;
    // ---- rescale (skippable) + PV: oacc[c][q] += V[c][k] * P[q][k] ----
    float aq[4];
#pragma unroll
    for (int qt = 0; qt < 4; ++qt) aq[qt] = alds[16 * qt + l15];
    const bool need = (aq[0] != 1.f) || (aq[1] != 1.f) || (aq[2] != 1.f) || (aq[3] != 1.f);
    if (__any(need)) {
#pragma unroll
      for (int ct = 0; ct < 4; ++ct)
#pragma unroll
        for (int qt = 0; qt < 4; ++qt) oacc[ct][qt] *= aq[qt];
    }
#pragma unroll
    for (int kk = 0; kk < 2; ++kk) {
      f16x8 bp[4];
#pragma unroll
      for (int qt = 0; qt < 4; ++qt) {
        const int q = 16 * qt + l15;
        bp[qt] = *(const f16x8*)((const char*)P + q * 144 + kk * 64 + lg * 16);
      }
#pragma unroll
      for (int ct = 0; ct < 4; ++ct)
#pragma unroll
        for (int qt = 0; qt < 4; ++qt)
          oacc[ct][qt] =
              __builtin_amdgcn_mfma_f32_16x16x32_f16(vpre[ct][kk], bp[qt], oacc[ct][qt], 0, 0, 0);
    }
  }
#undef QKHALF
  // ---- epilogue: divide by l, store transposed [q][c] ----
  if (wk == 0 && lane < 16) llds[16 * wq + lane] = l_run;
  __syncthreads();
  float inv[4];
#pragma unroll
  for (int qt = 0; qt < 4; ++qt) inv[qt] = 1.f / llds[16 * qt + l15];
#pragma unroll
  for (int ct = 0; ct < 4; ++ct)
#pragma unroll
    for (int qt = 0; qt < 4; ++qt) {
      alignas(8) f16_t o4[4];
#pragma unroll
      for (int j = 0; j < 4; ++j) o4[j] = (f16_t)(oacc[ct][qt][j] * inv[qt]);
      *(uint2*)(Oat_t + ((size_t)b * 4096 + q0 + 16 * qt + l15) * 512 + 64 * w + 16 * ct + 4 * lg) =
          *(const uint2*)o4;
    }
}

// ---------------- host launch ----------------
extern "C" void kernel_launch(void* const* d_in, const int* in_sizes, int n_in,
                              void* d_out, int out_size, void* d_ws, size_t ws_size,
                              hipStream_t stream) {
  const float* x = (const float*)d_in[0];
  const float* fw = (const float*)d_in[1];
  const float* fb = (const float*)d_in[2];
  const float* gw = (const float*)d_in[3];
  const float* gb = (const float*)d_in[4];
  const float* hw = (const float*)d_in[5];
  const float* hb = (const float*)d_in[6];
  const float* ow = (const float*)d_in[7];
  const float* ob = (const float*)d_in[8];
  float* out = (float*)d_out;
  (void)gb;

  const size_t BIG = (size_t)4 * 4096 * 512 * sizeof(f16_t);  // 16.78MB
  char* p = (char*)d_ws;
  float* mu = (float*)p; p += 2048 * sizeof(float);
  float* rs = (float*)p; p += 2048 * sizeof(float);
  float* vv = (float*)p; p += 512 * sizeof(float);
  float* b2 = (float*)p; p += 512 * sizeof(float);
  float* uu = (float*)p; p += (size_t)4 * 4096 * sizeof(float);
  f16_t* Mh = (f16_t*)p; p += (size_t)512 * 512 * sizeof(f16_t);
  f16_t* Wf = (f16_t*)p; p += (size_t)512 * 512 * sizeof(f16_t);
  f16_t* xf = (f16_t*)p; p += BIG;
  f16_t* xv = (f16_t*)p; p += BIG;
  f16_t* Zf = (f16_t*)p; p += BIG;
  f16_t* Oat_t = (f16_t*)p; p += BIG;  // total ~68MB

  const long sD = (long)4096 * 512;

  stats_k<<<2048, 256, 0, stream>>>(x, mu, rs, xv);
  prep_k<<<132, 256, 0, stream>>>(fw, gw, hw, ow, fb, hb, ob, Mh, Wf, vv, b2);
  normt_k<<<dim3(64, 8, 4), 256, 0, stream>>>(x, mu, rs, xf);
  u_k<<<dim3(1024, 4), 256, 0, stream>>>(vv, xf, uu);
  // Z[b][n][j] = sum_i xf[n][i] * Mh[j][i]
  gemm_k<f16_t, 0, false><<<dim3(4, 32, 4), 256, 0, stream>>>(
      xf, Mh, Zf, nullptr, nullptr, nullptr, sD, 0, sD, 512);
  // attention (256 blocks x 512 threads), V = xv (raw x) -> Oat_t[b][q][c]
  flash_k<<<256, 512, 0, stream>>>(Zf, xf, uu, xv, Oat_t);
  // out[b][o][n] = W . Oat_t^T + bias2 + x, fp32
  gemm_k<float, 1, true><<<dim3(32, 4, 4), 256, 0, stream>>>(
      Wf, Oat_t, out, b2, nullptr, x, 0, sD, sD, 4096);

  (void)in_sizes; (void)n_in; (void)out_size; (void)ws_size;
}

// Round 15
// 364.704 us; speedup vs baseline: 1.0756x; 1.0756x over previous
//
#include <hip/hip_runtime.h>

// Content_SA: instance-norm -> f/g/h 1x1 convs -> attention(QK^T softmax, PV) -> o conv + residual.
// B=4, C=512, H=W=64 (N=4096).
// Algebra: energy[n,m] = xn(n)^T M xn(m) + u[m] (+ query-const, cancels), M = f_w^T g_w (fp32).
//          out = W.(x.att^T) + bias2 + x, W = o_w.h_w (fp32), bias2 = o_w.h_b + o_b.
// Precision: M,W,Z,xn,x_v all f16 (single rounding from fp32-grade values); softmax fp32.
// R15 = R14 host structure (merged prep_k; non-flash 95us) + R13 flash verbatim (269us,
// spill-free 128 VGPR + 64 AGPR). QK parity-split REFUTED twice (R12, R14): +16 VGPR ->
// spill (WRITE_SIZE 16.4->18.4MB) > ILP gain; MFMA latency already hidden by 2 waves/SIMD.

typedef __bf16 bf16_t;
typedef _Float16 f16_t;
typedef _Float16 f16x8 __attribute__((ext_vector_type(8)));
typedef float f32x4 __attribute__((ext_vector_type(4)));

#define LOG2E 1.44269504088896340736f

__device__ __forceinline__ void gload16(const void* g, void* l) {
  __builtin_amdgcn_global_load_lds(
      (const __attribute__((address_space(1))) void*)g,
      (__attribute__((address_space(3))) void*)l, 16, 0, 0);
}

// ---------------- instance-norm statistics + x -> f16 cast (xv[b][c][n]) ----------------
__global__ void __launch_bounds__(256) stats_k(const float* __restrict__ x,
                                               float* __restrict__ mu,
                                               float* __restrict__ rs,
                                               f16_t* __restrict__ xv) {
  const int bc = blockIdx.x;
  const float4* row = (const float4*)(x + (size_t)bc * 4096);
  f16_t* vrow = xv + (size_t)bc * 4096;
  float s = 0.f, ss = 0.f;
  for (int i = threadIdx.x; i < 1024; i += 256) {
    float4 v = row[i];
    s += v.x + v.y + v.z + v.w;
    ss += v.x * v.x + v.y * v.y + v.z * v.z + v.w * v.w;
    alignas(8) f16_t h[4];
    h[0] = (f16_t)v.x; h[1] = (f16_t)v.y; h[2] = (f16_t)v.z; h[3] = (f16_t)v.w;
    *(uint2*)(vrow + i * 4) = *(const uint2*)h;
  }
#pragma unroll
  for (int o = 32; o >= 1; o >>= 1) {
    s += __shfl_down(s, o);
    ss += __shfl_down(ss, o);
  }
  __shared__ float as_[4], ass_[4];
  const int w = threadIdx.x >> 6;
  if ((threadIdx.x & 63) == 0) { as_[w] = s; ass_[w] = ss; }
  __syncthreads();
  if (threadIdx.x == 0) {
    float st = as_[0] + as_[1] + as_[2] + as_[3];
    float sst = ass_[0] + ass_[1] + ass_[2] + ass_[3];
    float m = st * (1.f / 4096.f);
    float var = sst * (1.f / 4096.f) - m * m;
    mu[bc] = m;
    rs[bc] = rsqrtf(var + 1e-5f);
  }
}

// ---------------- merged weight-prep: M, W, v, bias2 in ONE launch (132 blocks) ----------------
__device__ void mt_body(const float* __restrict__ A, const float* __restrict__ B,
                        f16_t* __restrict__ Out, int it, int jt, float* sm, bool bIsJK) {
  float* Fs = sm;          // [32][64]
  float* Gs = sm + 2048;   // bIsJK ? [64][33] : [32][64]
  const int t = threadIdx.x;
  float acc[16];
#pragma unroll
  for (int i = 0; i < 16; ++i) acc[i] = 0.f;
  const int jl = t >> 2, ib = (t & 3) * 16;
  const int lr = t >> 4, lc4 = (t & 15) * 4;
  for (int cc = 0; cc < 16; ++cc) {
    __syncthreads();
#pragma unroll
    for (int rep = 0; rep < 2; ++rep) {
      const int r = lr + rep * 16;
      *(float4*)&Fs[r * 64 + lc4] = *(const float4*)(A + (size_t)(cc * 32 + r) * 512 + it * 64 + lc4);
      if (!bIsJK)
        *(float4*)&Gs[r * 64 + lc4] = *(const float4*)(B + (size_t)(cc * 32 + r) * 512 + jt * 64 + lc4);
    }
    if (bIsJK) {
      const int oj = t >> 2, ok = (t & 3) * 8;
      const float4 a = *(const float4*)(B + (size_t)(jt * 64 + oj) * 512 + cc * 32 + ok);
      const float4 bq = *(const float4*)(B + (size_t)(jt * 64 + oj) * 512 + cc * 32 + ok + 4);
      Gs[oj * 33 + ok] = a.x; Gs[oj * 33 + ok + 1] = a.y;
      Gs[oj * 33 + ok + 2] = a.z; Gs[oj * 33 + ok + 3] = a.w;
      Gs[oj * 33 + ok + 4] = bq.x; Gs[oj * 33 + ok + 5] = bq.y;
      Gs[oj * 33 + ok + 6] = bq.z; Gs[oj * 33 + ok + 7] = bq.w;
    }
    __syncthreads();
#pragma unroll
    for (int c = 0; c < 32; ++c) {
      const float gv = bIsJK ? Gs[jl * 33 + c] : Gs[c * 64 + jl];
#pragma unroll
      for (int ii = 0; ii < 16; ++ii) acc[ii] += gv * Fs[c * 64 + ib + ii];
    }
  }
  alignas(16) f16_t hi[16];
#pragma unroll
  for (int ii = 0; ii < 16; ++ii) hi[ii] = (f16_t)acc[ii];
  const size_t o = (size_t)(jt * 64 + jl) * 512 + it * 64 + ib;
  *(uint4*)(Out + o) = *(const uint4*)hi;
  *(uint4*)(Out + o + 8) = *(const uint4*)(hi + 8);
}

__global__ void __launch_bounds__(256) prep_k(const float* __restrict__ fw,
                                              const float* __restrict__ gw,
                                              const float* __restrict__ hw,
                                              const float* __restrict__ ow,
                                              const float* __restrict__ fb,
                                              const float* __restrict__ hb,
                                              const float* __restrict__ ob,
                                              f16_t* __restrict__ Mh,
                                              f16_t* __restrict__ Wf,
                                              float* __restrict__ vv,
                                              float* __restrict__ b2) {
  __shared__ float sm[2048 + 64 * 33];
  const int bb = blockIdx.x;
  if (bb < 64) {
    mt_body(fw, gw, Mh, bb & 7, bb >> 3, sm, false);        // M^T[j][i] = sum_c fw[c][i] gw[c][j]
  } else if (bb < 128) {
    mt_body(hw, ow, Wf, (bb - 64) & 7, (bb - 64) >> 3, sm, true);  // W[j][i] = sum_k ow[j][k] hw[k][i]
  } else if (bb < 130) {
    const int j = (bb - 128) * 256 + threadIdx.x;
    float s = 0.f;
    for (int c = 0; c < 512; ++c) s += gw[(size_t)c * 512 + j] * fb[c];
    vv[j] = s;
  } else {
    const int j = (bb - 130) * 256 + threadIdx.x;
    float s = 0.f;
    for (int c = 0; c < 512; ++c) s += ow[(size_t)j * 512 + c] * hb[c];
    b2[j] = s + ob[j];
  }
}

// ---------------- u[b][m] = v . xn(m) ----------------
__global__ void __launch_bounds__(256) u_k(const float* __restrict__ v,
                                           const f16_t* __restrict__ xf,
                                           float* __restrict__ u) {
  const int w = threadIdx.x >> 6, lane = threadIdx.x & 63;
  const int m = blockIdx.x * 4 + w;
  const int b = blockIdx.y;
  const size_t o = ((size_t)b * 4096 + m) * 512 + lane * 8;
  const f16x8 vh = *(const f16x8*)(xf + o);
  const float4 v0 = *(const float4*)(v + lane * 8);
  const float4 v1 = *(const float4*)(v + lane * 8 + 4);
  float s = 0.f;
  const float* vp = &v0.x;
#pragma unroll
  for (int e = 0; e < 4; ++e) s += (float)vh[e] * vp[e];
  const float* vq = &v1.x;
#pragma unroll
  for (int e = 0; e < 4; ++e) s += (float)vh[4 + e] * vq[e];
#pragma unroll
  for (int o2 = 32; o2 >= 1; o2 >>= 1) s += __shfl_down(s, o2);
  if (lane == 0) u[(size_t)b * 4096 + m] = s;
}

// ---------------- normalize + transpose: x[b][c][n] -> xf (norm f16) [b][n][c] ----------------
__global__ void __launch_bounds__(256) normt_k(const float* __restrict__ x,
                                               const float* __restrict__ mu,
                                               const float* __restrict__ rs,
                                               f16_t* __restrict__ xf) {
  __shared__ float tile[64][65];
  const int t = threadIdx.x;
  const int nt = blockIdx.x, ct = blockIdx.y, b = blockIdx.z;
  const float* src = x + ((size_t)b * 512 + ct * 64) * 4096 + nt * 64;
  {
    const int r = t >> 4, cq = (t & 15) * 4;
#pragma unroll
    for (int it = 0; it < 4; ++it) {
      const int rr = r + it * 16;
      const float4 v = *(const float4*)(src + (size_t)rr * 4096 + cq);
      tile[rr][cq] = v.x; tile[rr][cq + 1] = v.y;
      tile[rr][cq + 2] = v.z; tile[rr][cq + 3] = v.w;
    }
  }
  __syncthreads();
  const int n = t & 63, ch = t >> 6;
  alignas(16) f16_t vf[16];
#pragma unroll
  for (int i = 0; i < 16; ++i) {
    const int c = ch * 16 + i;
    const float v = tile[c][n];
    const int gc = b * 512 + ct * 64 + c;
    vf[i] = (f16_t)((v - mu[gc]) * rs[gc]);
  }
  const size_t o = ((size_t)b * 4096 + nt * 64 + n) * 512 + ct * 64 + ch * 16;
  *(uint4*)(xf + o) = *(const uint4*)vf;
  *(uint4*)(xf + o + 8) = *(const uint4*)(vf + 8);
}

// ---------------- f16 GEMM (double-buffered, stage-ahead): C[m][n] = A[m][k].Bt[n][k], K=512 ----------------
template <typename OT, int BIAS, bool RESID>
__global__ void __launch_bounds__(256) gemm_k(const f16_t* __restrict__ A,
                                              const f16_t* __restrict__ Bt,
                                              OT* __restrict__ C,
                                              const float* __restrict__ biasM,
                                              const float* __restrict__ biasN,
                                              const float* __restrict__ resid,
                                              long sAb, long sBb, long sCb, int ldC) {
  __shared__ alignas(16) f16_t As[2][128 * 64];
  __shared__ alignas(16) f16_t Bs[2][128 * 64];
  const int t = threadIdx.x;
  const int lane = t & 63;
  const int w = t >> 6;
  const int wr = w >> 1, wc = w & 1;
  const int l15 = lane & 15, lg = lane >> 4;
  const int b = blockIdx.z;
  const int m0 = blockIdx.y * 128, n0 = blockIdx.x * 128;
  const f16_t* Ab = A + (size_t)sAb * b + (size_t)m0 * 512;
  const f16_t* Bb = Bt + (size_t)sBb * b + (size_t)n0 * 512;
  const int srow = t >> 3;
  const int slot = t & 7;

  auto gstage = [&](int pb_, int ks_) {
#pragma unroll
    for (int r_ = 0; r_ < 4; ++r_) {
      const int rr_ = r_ * 32 + srow;
      const size_t go_ = (size_t)rr_ * 512 + ks_ * 64 + ((slot ^ (rr_ & 7)) * 8);
      gload16(Ab + go_, (char*)As[pb_] + r_ * 4096 + w * 1024);
      gload16(Bb + go_, (char*)Bs[pb_] + r_ * 4096 + w * 1024);
    }
  };

  const f32x4 z4 = {0.f, 0.f, 0.f, 0.f};
  f32x4 acc[4][4];
#pragma unroll
  for (int i = 0; i < 4; ++i)
#pragma unroll
    for (int j = 0; j < 4; ++j) acc[i][j] = z4;

  gstage(0, 0);
  __syncthreads();
  for (int ks = 0; ks < 8; ++ks) {
    const int pb = ks & 1;
    if (ks < 7) gstage(pb ^ 1, ks + 1);
#pragma unroll
    for (int kk = 0; kk < 2; ++kk) {
      f16x8 af[4], bfr[4];
#pragma unroll
      for (int i = 0; i < 4; ++i) {
        const int ra = wr * 64 + i * 16 + l15;
        af[i] = *(const f16x8*)((const char*)As[pb] + ra * 128 + (((kk * 4 + lg) ^ (ra & 7)) * 16));
        const int rb = wc * 64 + i * 16 + l15;
        bfr[i] = *(const f16x8*)((const char*)Bs[pb] + rb * 128 + (((kk * 4 + lg) ^ (rb & 7)) * 16));
      }
#pragma unroll
      for (int i = 0; i < 4; ++i)
#pragma unroll
        for (int j = 0; j < 4; ++j)
          acc[i][j] = __builtin_amdgcn_mfma_f32_16x16x32_f16(af[i], bfr[j], acc[i][j], 0, 0, 0);
    }
    __syncthreads();
  }
  OT* Cb = C + (size_t)sCb * b;
#pragma unroll
  for (int i = 0; i < 4; ++i) {
#pragma unroll
    for (int j = 0; j < 4; ++j) {
      const int n = n0 + wc * 64 + j * 16 + l15;
      float bn = 0.f;
      if (BIAS == 2) bn = biasN[n];
#pragma unroll
      for (int r = 0; r < 4; ++r) {
        const int m = m0 + wr * 64 + i * 16 + lg * 4 + r;
        float v = acc[i][j][r] + bn;
        if (BIAS == 1) v += biasM[m];
        if (RESID) v += resid[(size_t)sCb * b + (size_t)m * ldC + n];
        Cb[(size_t)m * ldC + n] = (OT)v;
      }
    }
  }
}

// ---------------- flash attention (R13 verbatim, frozen): V = xv (raw x, f16) ----------------
// Q=Z[b][q][c] f16 in regs; K=xf[b][k][c] f16, LDS ch-half ping-pong (2x32KB); V=xv[b][c][k]
// reg-prefetch; out Oat_t[b][q][c]. 8 waves: wq=w&3 (16 q), wk=w>>2 (32 keys). 64 tiles.
__global__ void __launch_bounds__(512, 1) flash_k(const f16_t* __restrict__ Z,
                                                  const f16_t* __restrict__ X,
                                                  const float* __restrict__ u,
                                                  const f16_t* __restrict__ Hv,
                                                  f16_t* __restrict__ Oat_t) {
  __shared__ alignas(16) f16_t K[2][64 * 256];  // 2 x 32KB, 512B rows, slot-swizzled
  __shared__ alignas(16) f16_t P[64 * 72];      // 9KB, 144B rows (2-way bank alias = free)
  __shared__ float redm[4][2][16];
  __shared__ float reds[4][2][16];
  __shared__ float alds[64];
  __shared__ float llds[64];

  const int t = threadIdx.x;
  const int lane = t & 63;
  const int w = t >> 6;
  const int wq = w & 3, wk = w >> 2;
  const int l15 = lane & 15, lg = lane >> 4;
  const int bid = blockIdx.x;
  const int xcd = bid & 7;
  const int b = xcd >> 1;
  const int q0 = ((xcd & 1) * 32 + (bid >> 3)) * 64;

  const f16_t* Kb = X + (size_t)b * 4096 * 512;
  const f16_t* Vb = Hv + (size_t)b * 512 * 4096;
  const float* ub = u + (size_t)b * 4096;

  const int srow = w * 2 + (lane >> 5);
  const int slot32 = lane & 31;

  auto stagek = [&](int pb_, int kt_, int hf_) {
    const int k0_ = kt_ * 64;
#pragma unroll
    for (int r_ = 0; r_ < 4; ++r_) {
      const int row_ = r_ * 16 + srow;
      const size_t go_ = (size_t)(k0_ + row_) * 512 + hf_ * 256 + ((slot32 ^ (row_ & 7)) * 8);
      gload16(Kb + go_, (char*)K[pb_] + r_ * 8192 + w * 1024);
    }
  };

// QK on buffer PB, channel-half HF: 16 MFMA (simple 2-chain form -- the spill-free optimum)
#define QKHALF(PB, HF)                                                                        \
  do {                                                                                        \
    _Pragma("unroll") for (int cwl_ = 0; cwl_ < 8; ++cwl_) {                                  \
      const f16x8 qf_ = qf[(HF) * 8 + cwl_];                                                  \
      _Pragma("unroll") for (int mf_ = 0; mf_ < 2; ++mf_) {                                   \
        const int key_ = 32 * wk + 16 * mf_ + l15;                                            \
        const int so_ = ((cwl_ * 4 + lg) ^ (key_ & 7)) * 16;                                  \
        const f16x8 kf_ = *(const f16x8*)((const char*)K[PB] + key_ * 512 + so_);             \
        sacc[mf_] = __builtin_amdgcn_mfma_f32_16x16x32_f16(kf_, qf_, sacc[mf_], 0, 0, 0);     \
      }                                                                                       \
    }                                                                                         \
  } while (0)

  // Q fragments in registers: q = q0 + 16*wq + l15, ch window cw*32 + lg*8
  f16x8 qf[16];
  {
    const size_t qo = ((size_t)b * 4096 + q0 + 16 * wq + l15) * 512 + lg * 8;
#pragma unroll
    for (int cw = 0; cw < 16; ++cw) qf[cw] = *(const f16x8*)(Z + qo + cw * 32);
  }
  stagek(0, 0, 0);

  const f32x4 z4 = {0.f, 0.f, 0.f, 0.f};
  f32x4 oacc[4][4];
#pragma unroll
  for (int i = 0; i < 4; ++i)
#pragma unroll
    for (int j = 0; j < 4; ++j) oacc[i][j] = z4;
  float m_run = -3.0e38f, l_run = 0.f;
  const int qrow = 16 * wq + l15;

  __syncthreads();  // buf0.half0 ready

  for (int kt = 0; kt < 64; ++kt) {
    const int k0 = kt * 64;
    f32x4 sacc[2] = {z4, z4};
    // u for this wave's 32 keys (register loads)
    const float4 u0 = *(const float4*)(ub + k0 + 32 * wk + 4 * lg);
    const float4 u1 = *(const float4*)(ub + k0 + 32 * wk + 16 + 4 * lg);
    stagek(1, kt, 1);  // half1 -> buf1, flies under QK0
    QKHALF(0, 0);
    __syncthreads();   // buf1 ready
    if (kt < 63) stagek(0, kt + 1, 0);  // next half0 -> buf0, flies under QK1+softmax
    // V prefetch for this tile
    f16x8 vpre[4][2];
#pragma unroll
    for (int ct = 0; ct < 4; ++ct) {
      const int c = 64 * w + 16 * ct + l15;
#pragma unroll
      for (int kk = 0; kk < 2; ++kk)
        vpre[ct][kk] = *(const f16x8*)(Vb + (size_t)c * 4096 + k0 + kk * 32 + lg * 8);
    }
    QKHALF(1, 1);
    // ---- u bias + per-lane max ----
    float pm = -3.0e38f;
    {
      const float* up0 = &u0.x;
      const float* up1 = &u1.x;
#pragma unroll
      for (int j = 0; j < 4; ++j) {
        sacc[0][j] += up0[j];
        sacc[1][j] += up1[j];
        pm = fmaxf(pm, fmaxf(sacc[0][j], sacc[1][j]));
      }
    }
    pm = fmaxf(pm, __shfl_xor(pm, 16));
    pm = fmaxf(pm, __shfl_xor(pm, 32));
    if (lane < 16) redm[wq][wk][lane] = pm;
    __syncthreads();
    // ---- softmax with defer-max (THR=8) ----
    const float m_tile = fmaxf(pm, redm[wq][wk ^ 1][l15]);
    float alpha;
    if (m_tile > m_run + 8.f) {
      alpha = exp2f((m_run - m_tile) * LOG2E);
      m_run = m_tile;
    } else {
      alpha = 1.f;
    }
    float ps = 0.f;
    {
      alignas(8) f16_t pk[4];
#pragma unroll
      for (int mf = 0; mf < 2; ++mf) {
#pragma unroll
        for (int j = 0; j < 4; ++j) {
          const float p = exp2f((sacc[mf][j] - m_run) * LOG2E);
          ps += p;
          pk[j] = (f16_t)p;
        }
        *(uint2*)((char*)P + qrow * 144 + 64 * wk + 32 * mf + 8 * lg) = *(const uint2*)pk;
      }
    }
    ps += __shfl_xor(ps, 16);
    ps += __shfl_xor(ps, 32);
    if (lane < 16) {
      reds[wq][wk][lane] = ps;
      if (wk == 0) alds[16 * wq + lane] = alpha;
    }
    __syncthreads();  // P / reds / alds ready
    const float s_tile = reds[wq][0][l15] + reds[wq][1][l15];
    l_run = l_run * alpha + s_tile;
    // ---- rescale (skippable) + PV: oacc[c][q] += V[c][k] * P[q][k] ----
    float aq[4];
#pragma unroll
    for (int qt = 0; qt < 4; ++qt) aq[qt] = alds[16 * qt + l15];
    const bool need = (aq[0] != 1.f) || (aq[1] != 1.f) || (aq[2] != 1.f) || (aq[3] != 1.f);
    if (__any(need)) {
#pragma unroll
      for (int ct = 0; ct < 4; ++ct)
#pragma unroll
        for (int qt = 0; qt < 4; ++qt) oacc[ct][qt] *= aq[qt];
    }
#pragma unroll
    for (int kk = 0; kk < 2; ++kk) {
      f16x8 bp[4];
#pragma unroll
      for (int qt = 0; qt < 4; ++qt) {
        const int q = 16 * qt + l15;
        bp[qt] = *(const f16x8*)((const char*)P + q * 144 + kk * 64 + lg * 16);
      }
#pragma unroll
      for (int ct = 0; ct < 4; ++ct)
#pragma unroll
        for (int qt = 0; qt < 4; ++qt)
          oacc[ct][qt] =
              __builtin_amdgcn_mfma_f32_16x16x32_f16(vpre[ct][kk], bp[qt], oacc[ct][qt], 0, 0, 0);
    }
  }
#undef QKHALF
  // ---- epilogue: divide by l, store transposed [q][c] ----
  if (wk == 0 && lane < 16) llds[16 * wq + lane] = l_run;
  __syncthreads();
  float inv[4];
#pragma unroll
  for (int qt = 0; qt < 4; ++qt) inv[qt] = 1.f / llds[16 * qt + l15];
#pragma unroll
  for (int ct = 0; ct < 4; ++ct)
#pragma unroll
    for (int qt = 0; qt < 4; ++qt) {
      alignas(8) f16_t o4[4];
#pragma unroll
      for (int j = 0; j < 4; ++j) o4[j] = (f16_t)(oacc[ct][qt][j] * inv[qt]);
      *(uint2*)(Oat_t + ((size_t)b * 4096 + q0 + 16 * qt + l15) * 512 + 64 * w + 16 * ct + 4 * lg) =
          *(const uint2*)o4;
    }
}

// ---------------- host launch ----------------
extern "C" void kernel_launch(void* const* d_in, const int* in_sizes, int n_in,
                              void* d_out, int out_size, void* d_ws, size_t ws_size,
                              hipStream_t stream) {
  const float* x = (const float*)d_in[0];
  const float* fw = (const float*)d_in[1];
  const float* fb = (const float*)d_in[2];
  const float* gw = (const float*)d_in[3];
  const float* gb = (const float*)d_in[4];
  const float* hw = (const float*)d_in[5];
  const float* hb = (const float*)d_in[6];
  const float* ow = (const float*)d_in[7];
  const float* ob = (const float*)d_in[8];
  float* out = (float*)d_out;
  (void)gb;

  const size_t BIG = (size_t)4 * 4096 * 512 * sizeof(f16_t);  // 16.78MB
  char* p = (char*)d_ws;
  float* mu = (float*)p; p += 2048 * sizeof(float);
  float* rs = (float*)p; p += 2048 * sizeof(float);
  float* vv = (float*)p; p += 512 * sizeof(float);
  float* b2 = (float*)p; p += 512 * sizeof(float);
  float* uu = (float*)p; p += (size_t)4 * 4096 * sizeof(float);
  f16_t* Mh = (f16_t*)p; p += (size_t)512 * 512 * sizeof(f16_t);
  f16_t* Wf = (f16_t*)p; p += (size_t)512 * 512 * sizeof(f16_t);
  f16_t* xf = (f16_t*)p; p += BIG;
  f16_t* xv = (f16_t*)p; p += BIG;
  f16_t* Zf = (f16_t*)p; p += BIG;
  f16_t* Oat_t = (f16_t*)p; p += BIG;  // total ~68MB

  const long sD = (long)4096 * 512;

  stats_k<<<2048, 256, 0, stream>>>(x, mu, rs, xv);
  prep_k<<<132, 256, 0, stream>>>(fw, gw, hw, ow, fb, hb, ob, Mh, Wf, vv, b2);
  normt_k<<<dim3(64, 8, 4), 256, 0, stream>>>(x, mu, rs, xf);
  u_k<<<dim3(1024, 4), 256, 0, stream>>>(vv, xf, uu);
  // Z[b][n][j] = sum_i xf[n][i] * Mh[j][i]
  gemm_k<f16_t, 0, false><<<dim3(4, 32, 4), 256, 0, stream>>>(
      xf, Mh, Zf, nullptr, nullptr, nullptr, sD, 0, sD, 512);
  // attention (256 blocks x 512 threads), V = xv (raw x) -> Oat_t[b][q][c]
  flash_k<<<256, 512, 0, stream>>>(Zf, xf, uu, xv, Oat_t);
  // out[b][o][n] = W . Oat_t^T + bias2 + x, fp32
  gemm_k<float, 1, true><<<dim3(32, 4, 4), 256, 0, stream>>>(
      Wf, Oat_t, out, b2, nullptr, x, 0, sD, sD, 4096);

  (void)in_sizes; (void)n_in; (void)out_size; (void)ws_size;
}